// Round 7
// baseline (584.427 us; speedup 1.0000x reference)
//
#include <hip/hip_runtime.h>

// SJLT projection: out[b, idx[d,j]] += x[b,d] * sign(d,j), * 1/sqrt(4)
// B=64, D=524288, P=8192, C=4.
//
// Measured walls (R1-R6):
//  - LDS fp32 atomics: ~3.2 cyc/lane serialized -> dead (R1-R3, 690us).
//  - Random 4B global stores: 64B HBM write each (no-allocate L2) (R4/R5).
//  - Same-line global atomics: ~40ns serialized; 2M ops over 512 lines
//    ~ 80us regardless of host kernel (R4 scatter, R6 transpose_hist).
// R7: kill the CSR. Single fused kernel: coalesced x tile -> LDS transpose
// -> per-d, one fully-coalesced 256B no-return global_atomic_add_f32 per
// (d,j) into outT[p][64] (2MB, 32k lines -> per-line load only ~256).
// Epilogue kernel un-transposes outT -> out. Full f32 (no bf16 step).

constexpr int BATCH = 64;
constexpr int DIM   = 524288;
constexpr int PROJ  = 8192;

constexpr int BLOCK  = 256;
constexpr int NBLK   = 1024;
constexpr int DPB    = DIM / NBLK;      // 512 d's per block
constexpr int TILE_D = 64;
constexpr int NTILES = DPB / TILE_D;    // 8

// ------------------------------------------------ fused transpose+scatter
__global__ __launch_bounds__(BLOCK) void sjlt_atomic_scatter(
    const float* __restrict__ x,
    const int4*  __restrict__ idx4,
    const int4*  __restrict__ sgn4,
    float*       __restrict__ outT)     // [PROJ][64], zeroed
{
    __shared__ float tile[64][65];      // [b][d_local], pad -> column reads 2-way (free)

    const int t    = threadIdx.x;
    const int lane = t & 63;
    const int w    = t >> 6;            // wave 0..3
    const int dblk = blockIdx.x * DPB;

    for (int tt = 0; tt < NTILES; ++tt) {
        const int d0 = dblk + tt * TILE_D;
        // load 64x64 f32 tile; each wave-instr = one 256B row segment
#pragma unroll
        for (int i = 0; i < 16; ++i) {
            const int fid = i * BLOCK + t;
            const int row = fid >> 6;       // b
            const int col = fid & 63;       // d_local
            tile[row][col] = x[(size_t)row * DIM + d0 + col] * 0.5f;
        }
        __syncthreads();

        // each wave owns 16 d's; per (d,j): one coalesced 256B atomic
#pragma unroll 1
        for (int m = 0; m < 16; ++m) {
            const int dl = w * 16 + m;
            const int d  = d0 + dl;
            const int4 iv = idx4[d];        // wave-uniform
            const int4 sv = sgn4[d];
            // x[b=lane][d]*0.5 ; banks (lane+dl)%32 -> 2-way, free
            const uint32_t u = __float_as_uint(tile[lane][dl]);
            unsafeAtomicAdd(&outT[(size_t)iv.x * 64 + lane],
                            __uint_as_float(u ^ ((uint32_t)(~sv.x & 1) << 31)));
            unsafeAtomicAdd(&outT[(size_t)iv.y * 64 + lane],
                            __uint_as_float(u ^ ((uint32_t)(~sv.y & 1) << 31)));
            unsafeAtomicAdd(&outT[(size_t)iv.z * 64 + lane],
                            __uint_as_float(u ^ ((uint32_t)(~sv.z & 1) << 31)));
            unsafeAtomicAdd(&outT[(size_t)iv.w * 64 + lane],
                            __uint_as_float(u ^ ((uint32_t)(~sv.w & 1) << 31)));
        }
        __syncthreads();                    // tile reused next iteration
    }
}

// ------------------------------------------------ outT[p][b] -> out[b][p]
__global__ __launch_bounds__(256) void untranspose_kernel(
    const float* __restrict__ outT, float* __restrict__ out)
{
    __shared__ float tl[64][65];
    const int p0 = blockIdx.x * 64;
    const int t  = threadIdx.x;
#pragma unroll
    for (int i = 0; i < 16; ++i) {
        const int fid = i * 256 + t;
        const int pr  = fid >> 6;           // p_local
        const int b   = fid & 63;
        tl[pr][b] = outT[(size_t)(p0 + pr) * 64 + b];
    }
    __syncthreads();
#pragma unroll
    for (int i = 0; i < 16; ++i) {
        const int fid = i * 256 + t;
        const int b   = fid >> 6;
        const int pl  = fid & 63;
        out[(size_t)b * PROJ + p0 + pl] = tl[pl][b];
    }
}

// ------------------------------------------------- fallback (R3 scatter)
__device__ __forceinline__ void lds_fadd(uint32_t byte_addr, float v) {
    asm volatile("ds_add_f32 %0, %1" :: "v"(byte_addr), "v"(v) : "memory");
}
__device__ __forceinline__ void lds_fadd_off32k(uint32_t byte_addr, float v) {
    asm volatile("ds_add_f32 %0, %1 offset:32768" :: "v"(byte_addr), "v"(v) : "memory");
}

__global__ __launch_bounds__(1024) void sjlt_scatter(
    const float* __restrict__ x, const int4* __restrict__ idx4,
    const int4* __restrict__ sgn4, float* __restrict__ out)
{
    __shared__ float acc[4 * PROJ];
    for (int i = threadIdx.x; i < 4 * PROJ; i += 1024) acc[i] = 0.0f;
    __syncthreads();
    const int row0 = blockIdx.y * 4;
    const int dbeg = blockIdx.x * (DIM / 16);
    const uint32_t accBase = (uint32_t)(uintptr_t)(&acc[0]);
    const float* xr0 = x + (size_t)(row0 + 0) * DIM;
    const float* xr1 = x + (size_t)(row0 + 1) * DIM;
    const float* xr2 = x + (size_t)(row0 + 2) * DIM;
    const float* xr3 = x + (size_t)(row0 + 3) * DIM;
    for (int d = dbeg + (int)threadIdx.x; d < dbeg + DIM / 16; d += 1024) {
        const int4 iv = idx4[d];
        const int4 sv = sgn4[d];
        const uint32_t u0 = __float_as_uint(xr0[d]);
        const uint32_t u1 = __float_as_uint(xr1[d]);
        const uint32_t u2 = __float_as_uint(xr2[d]);
        const uint32_t u3 = __float_as_uint(xr3[d]);
        const int p[4] = {iv.x, iv.y, iv.z, iv.w};
        const int s[4] = {sv.x, sv.y, sv.z, sv.w};
#pragma unroll
        for (int j = 0; j < 4; ++j) {
            const uint32_t flip = (uint32_t)(s[j] ^ 1) << 31;
            const uint32_t a01  = accBase + ((uint32_t)p[j] << 2);
            const uint32_t a23  = a01 + 2u * 32768u;
            lds_fadd        (a01, __uint_as_float(u0 ^ flip));
            lds_fadd_off32k (a01, __uint_as_float(u1 ^ flip));
            lds_fadd        (a23, __uint_as_float(u2 ^ flip));
            lds_fadd_off32k (a23, __uint_as_float(u3 ^ flip));
        }
    }
    __syncthreads();
    for (int i = threadIdx.x; i < 4 * PROJ; i += 1024) {
        const int r  = i >> 13;
        const int pp = i & (PROJ - 1);
        unsafeAtomicAdd(&out[(size_t)(row0 + r) * PROJ + pp], acc[i] * 0.5f);
    }
}

// --------------------------------------------------------------- launch
extern "C" void kernel_launch(void* const* d_in, const int* in_sizes, int n_in,
                              void* d_out, int out_size, void* d_ws, size_t ws_size,
                              hipStream_t stream) {
    const float* x   = (const float*)d_in[0];
    const int4*  idx = (const int4*) d_in[1];
    const int4*  sgn = (const int4*) d_in[2];
    float*       out = (float*)d_out;

    const size_t need = (size_t)PROJ * 64 * sizeof(float);   // 2 MiB
    if (ws_size >= need) {
        float* outT = (float*)d_ws;
        hipMemsetAsync(outT, 0, need, stream);               // ws is 0xAA-poisoned
        sjlt_atomic_scatter<<<NBLK,      BLOCK, 0, stream>>>(x, idx, sgn, outT);
        untranspose_kernel <<<PROJ / 64, 256,   0, stream>>>(outT, out);
    } else {
        // ws too small: R3 LDS-scatter path (passes at ~830 us)
        hipMemsetAsync(d_out, 0, (size_t)out_size * sizeof(float), stream);
        dim3 grid(16, 16);
        sjlt_scatter<<<grid, 1024, 0, stream>>>(x, idx, sgn, out);
    }
}

// Round 8
// 491.265 us; speedup vs baseline: 1.1896x; 1.1896x over previous
//
#include <hip/hip_runtime.h>

// SJLT projection: out[b, idx[d,j]] += x[b,d] * sign(d,j), * 1/sqrt(4)
// B=64, D=524288, P=8192, C=4.
//
// Measured walls (R1-R7):
//  - LDS atomics: ~3.16 cyc/lane, serialized pipe (R1-R3: 690us).
//  - Global atomics: ~40ns each AND 64B HBM write-through per line-RMW
//    (R4/R6: 2M ops ~ 80us; R7: 512MB WRITE_SIZE for 2MB outT).
//  - Random 4B global stores: 64B HBM write each (R4/R5).
// R8: owner-computes gather, deterministic binning (no hot-path atomics):
//  K1 transpose x -> xT bf16[D][64] (*0.5) + per-block LDS hist -> cnt
//  K2 per-bucket exclusive scan over blocks -> lofs, tot
//  K3 re-read idx/sgn, LDS-stage entries grouped by bucket, write u16
//     entries to deterministic segment slots (coalesced-ish runs)
//  K4 block-per-bucket gather: broadcast entries, coalesced xT loads,
//     non-atomic wave-private LDS accumulation, exclusive out writes.

constexpr int BATCH = 64;
constexpr int DIM   = 524288;
constexpr int PROJ  = 8192;
constexpr int NBUCK = 256;          // buckets of 32 p's
constexpr int NBLK  = 1024;         // d-chunks
constexpr int DPB   = DIM / NBLK;   // 512 d per chunk
constexpr int EPB   = DPB * 4;      // 2048 entries per chunk
constexpr int SEG   = 8896;         // u16 slots per bucket (8192 mean + ~7.8 sigma)

__device__ __forceinline__ uint32_t f2bf(float f) {   // RNE f32 -> bf16 bits
    uint32_t u = __float_as_uint(f);
    return (u + 0x7fffu + ((u >> 16) & 1u)) >> 16;
}

// --------------------------------------------- K1: transpose + count
__global__ __launch_bounds__(256) void k1_transpose_count(
    const float* __restrict__ x, const int4* __restrict__ idx4,
    uint32_t* __restrict__ xT32, uint32_t* __restrict__ cnt)
{
    __shared__ float tile[64][65];
    __shared__ uint32_t lcnt[NBUCK];
    const int t    = threadIdx.x;
    const int blk  = blockIdx.x;
    const int dblk = blk * DPB;

    lcnt[t] = 0;
    __syncthreads();

    {   // histogram this chunk's 2048 entries into 256 LDS counters
        int4 a = idx4[dblk + 2 * t];
        int4 b = idx4[dblk + 2 * t + 1];
        atomicAdd(&lcnt[a.x >> 5], 1u);
        atomicAdd(&lcnt[a.y >> 5], 1u);
        atomicAdd(&lcnt[a.z >> 5], 1u);
        atomicAdd(&lcnt[a.w >> 5], 1u);
        atomicAdd(&lcnt[b.x >> 5], 1u);
        atomicAdd(&lcnt[b.y >> 5], 1u);
        atomicAdd(&lcnt[b.z >> 5], 1u);
        atomicAdd(&lcnt[b.w >> 5], 1u);
    }

    for (int tt = 0; tt < 8; ++tt) {       // 8 tiles of 64 d
        const int d0 = dblk + tt * 64;
        __syncthreads();
#pragma unroll
        for (int i = 0; i < 16; ++i) {
            const int fid = i * 256 + t;
            const int row = fid >> 6;      // b
            const int col = fid & 63;      // d_local
            tile[row][col] = x[(size_t)row * DIM + d0 + col] * 0.5f;
        }
        __syncthreads();
#pragma unroll
        for (int i = 0; i < 8; ++i) {
            const int fid = i * 256 + t;   // 2048 u32 words
            const int dl  = fid >> 5;      // 0..63
            const int w   = fid & 31;
            const uint32_t lo = f2bf(tile[2 * w + 0][dl]);
            const uint32_t hi = f2bf(tile[2 * w + 1][dl]);
            xT32[(size_t)(d0 + dl) * 32 + w] = lo | (hi << 16);
        }
    }
    __syncthreads();
    cnt[(size_t)blk * NBUCK + t] = lcnt[t];      // block-major, coalesced
}

// --------------------------------------------- K2: per-bucket scan over blocks
__global__ __launch_bounds__(256) void k2_scan(
    const uint32_t* __restrict__ cnt, uint32_t* __restrict__ lofs,
    uint32_t* __restrict__ tot)
{
    __shared__ uint32_t wsum[4];
    const int q    = blockIdx.x;
    const int t    = threadIdx.x;
    const int lane = t & 63;
    uint32_t c[4], s = 0;
#pragma unroll
    for (int i = 0; i < 4; ++i) { c[i] = cnt[(size_t)(4 * t + i) * NBUCK + q]; s += c[i]; }
    uint32_t v = s;
#pragma unroll
    for (int off = 1; off < 64; off <<= 1) {
        uint32_t u = __shfl_up(v, off);
        if (lane >= off) v += u;
    }
    if (lane == 63) wsum[t >> 6] = v;
    __syncthreads();
    uint32_t wb = 0;
    for (int w0 = 0; w0 < (t >> 6); ++w0) wb += wsum[w0];
    uint32_t base = wb + v - s;
#pragma unroll
    for (int i = 0; i < 4; ++i) { lofs[(size_t)q * NBLK + 4 * t + i] = base; base += c[i]; }
    if (t == 255) tot[q] = base;
}

// --------------------------------------------- K3: deterministic entry scatter
__global__ __launch_bounds__(256) void k3_scatter(
    const int4* __restrict__ idx4, const int4* __restrict__ sgn4,
    const uint32_t* __restrict__ cnt, const uint32_t* __restrict__ lofs,
    uint16_t* __restrict__ entries)
{
    __shared__ uint16_t staged[EPB];       // 4 KB, grouped by bucket
    __shared__ uint32_t lbase[NBUCK];
    __shared__ uint32_t cur[NBUCK];
    __shared__ uint32_t gl[NBUCK];
    const int t    = threadIdx.x;
    const int blk  = blockIdx.x;
    const int dblk = blk * DPB;

    cur[t] = cnt[(size_t)blk * NBUCK + t];       // temp: this block's counts
    gl[t]  = lofs[(size_t)t * NBLK + blk];       // global base within segment
    __syncthreads();
    if (t < 64) {                                // wave-0 scan of 256 counts
        uint32_t c4[4], s = 0;
#pragma unroll
        for (int i = 0; i < 4; ++i) { c4[i] = cur[t * 4 + i]; s += c4[i]; }
        uint32_t v = s;
#pragma unroll
        for (int off = 1; off < 64; off <<= 1) {
            uint32_t u = __shfl_up(v, off);
            if ((t & 63) >= off) v += u;
        }
        uint32_t base = v - s;
#pragma unroll
        for (int i = 0; i < 4; ++i) { lbase[t * 4 + i] = base; base += c4[i]; }
    }
    __syncthreads();
    cur[t] = lbase[t];
    __syncthreads();

    int4 ia = idx4[dblk + 2 * t], ib = idx4[dblk + 2 * t + 1];
    int4 sa = sgn4[dblk + 2 * t], sb = sgn4[dblk + 2 * t + 1];
    const uint32_t dA = (uint32_t)(2 * t) << 6;
    const uint32_t dB = (uint32_t)(2 * t + 1) << 6;

    auto stage = [&](int p, int s, uint32_t dsh) {
        uint32_t q   = (uint32_t)p >> 5;
        uint32_t pos = atomicAdd(&cur[q], 1u);   // LDS cursor (cheap scale)
        staged[pos]  = (uint16_t)(dsh | ((uint32_t)(s & 1) << 5) | ((uint32_t)p & 31u));
    };
    stage(ia.x, sa.x, dA); stage(ia.y, sa.y, dA);
    stage(ia.z, sa.z, dA); stage(ia.w, sa.w, dA);
    stage(ib.x, sb.x, dB); stage(ib.y, sb.y, dB);
    stage(ib.z, sb.z, dB); stage(ib.w, sb.w, dB);
    __syncthreads();

    // thread t == bucket t: copy its grouped run to deterministic slots
    uint32_t c  = cur[t] - lbase[t];
    uint32_t g  = gl[t];
    if (g > SEG) g = SEG;
    uint32_t cap = (uint32_t)SEG - g;
    if (c > cap) c = cap;                        // overflow clamp (never at 7.8 sigma)
    uint16_t* dst = entries + (size_t)t * SEG + g;
    const uint32_t lb = lbase[t];
    for (uint32_t k = 0; k < c; ++k) dst[k] = staged[lb + k];
}

// --------------------------------------------- K4: gather (block = bucket)
__global__ __launch_bounds__(512) void k4_gather(
    const uint16_t* __restrict__ entries, const uint32_t* __restrict__ lofs,
    const uint32_t* __restrict__ tot, const uint16_t* __restrict__ xT16,
    float* __restrict__ out)
{
    __shared__ float acc[8][32 * 65];            // 66.5 KB, wave-private, padded
    const int t    = threadIdx.x;
    const int w    = t >> 6;                     // wave 0..7
    const int lane = t & 63;                     // lane = batch b
    const int q    = blockIdx.x;
    float* aw = acc[w];

    for (int i = t; i < 8 * 32 * 65; i += 512) ((float*)acc)[i] = 0.f;
    __syncthreads();

    const uint32_t qbase = (uint32_t)q * SEG;
    const uint32_t total = tot[q];

    for (int blk = w; blk < NBLK; blk += 8) {
        uint32_t start = lofs[(size_t)q * NBLK + blk];
        uint32_t end   = (blk == NBLK - 1) ? total : lofs[(size_t)q * NBLK + blk + 1];
        if (start > SEG) start = SEG;
        if (end   > SEG) end   = SEG;
        const uint32_t dbase = (uint32_t)blk * DPB;

        for (uint32_t i0 = start; i0 < end; i0 += 64) {
            const uint32_t ev = entries[qbase + i0 + (uint32_t)lane];  // coalesced 128B
            uint32_t m = end - i0; if (m > 64u) m = 64u;
            uint32_t i = 0;
            for (; i + 4 <= m; i += 4) {         // 4 xT loads in flight
                const uint32_t e0 = __shfl(ev, (int)(i + 0));
                const uint32_t e1 = __shfl(ev, (int)(i + 1));
                const uint32_t e2 = __shfl(ev, (int)(i + 2));
                const uint32_t e3 = __shfl(ev, (int)(i + 3));
                const uint32_t u0 = xT16[(size_t)(dbase + (e0 >> 6)) * 64 + lane];
                const uint32_t u1 = xT16[(size_t)(dbase + (e1 >> 6)) * 64 + lane];
                const uint32_t u2 = xT16[(size_t)(dbase + (e2 >> 6)) * 64 + lane];
                const uint32_t u3 = xT16[(size_t)(dbase + (e3 >> 6)) * 64 + lane];
                float f0 = __uint_as_float(u0 << 16); f0 = (e0 & 32u) ? f0 : -f0;
                float f1 = __uint_as_float(u1 << 16); f1 = (e1 & 32u) ? f1 : -f1;
                float f2 = __uint_as_float(u2 << 16); f2 = (e2 & 32u) ? f2 : -f2;
                float f3 = __uint_as_float(u3 << 16); f3 = (e3 & 32u) ? f3 : -f3;
                aw[(e0 & 31u) * 65 + lane] += f0;    // non-atomic: lane-unique,
                aw[(e1 & 31u) * 65 + lane] += f1;    // wave-sequential
                aw[(e2 & 31u) * 65 + lane] += f2;
                aw[(e3 & 31u) * 65 + lane] += f3;
            }
            for (; i < m; ++i) {
                const uint32_t e = __shfl(ev, (int)i);
                const uint32_t u = xT16[(size_t)(dbase + (e >> 6)) * 64 + lane];
                float f = __uint_as_float(u << 16); f = (e & 32u) ? f : -f;
                aw[(e & 31u) * 65 + lane] += f;
            }
        }
    }
    __syncthreads();

    // reduce 8 wave-accs, write exclusive out slice (full coverage, no memset)
#pragma unroll
    for (int pass = 0; pass < 4; ++pass) {
        const int b  = pass * 16 + (t >> 5);
        const int pl = t & 31;
        const int j  = pl * 65 + b;
        float v = acc[0][j] + acc[1][j] + acc[2][j] + acc[3][j]
                + acc[4][j] + acc[5][j] + acc[6][j] + acc[7][j];
        out[(size_t)b * PROJ + q * 32 + pl] = v;
    }
}

// ------------------------------------------------- fallback (R3 scatter)
__device__ __forceinline__ void lds_fadd(uint32_t byte_addr, float v) {
    asm volatile("ds_add_f32 %0, %1" :: "v"(byte_addr), "v"(v) : "memory");
}
__device__ __forceinline__ void lds_fadd_off32k(uint32_t byte_addr, float v) {
    asm volatile("ds_add_f32 %0, %1 offset:32768" :: "v"(byte_addr), "v"(v) : "memory");
}

__global__ __launch_bounds__(1024) void sjlt_scatter(
    const float* __restrict__ x, const int4* __restrict__ idx4,
    const int4* __restrict__ sgn4, float* __restrict__ out)
{
    __shared__ float acc[4 * PROJ];
    for (int i = threadIdx.x; i < 4 * PROJ; i += 1024) acc[i] = 0.0f;
    __syncthreads();
    const int row0 = blockIdx.y * 4;
    const int dbeg = blockIdx.x * (DIM / 16);
    const uint32_t accBase = (uint32_t)(uintptr_t)(&acc[0]);
    const float* xr0 = x + (size_t)(row0 + 0) * DIM;
    const float* xr1 = x + (size_t)(row0 + 1) * DIM;
    const float* xr2 = x + (size_t)(row0 + 2) * DIM;
    const float* xr3 = x + (size_t)(row0 + 3) * DIM;
    for (int d = dbeg + (int)threadIdx.x; d < dbeg + DIM / 16; d += 1024) {
        const int4 iv = idx4[d];
        const int4 sv = sgn4[d];
        const uint32_t u0 = __float_as_uint(xr0[d]);
        const uint32_t u1 = __float_as_uint(xr1[d]);
        const uint32_t u2 = __float_as_uint(xr2[d]);
        const uint32_t u3 = __float_as_uint(xr3[d]);
        const int p[4] = {iv.x, iv.y, iv.z, iv.w};
        const int s[4] = {sv.x, sv.y, sv.z, sv.w};
#pragma unroll
        for (int j = 0; j < 4; ++j) {
            const uint32_t flip = (uint32_t)(s[j] ^ 1) << 31;
            const uint32_t a01  = accBase + ((uint32_t)p[j] << 2);
            const uint32_t a23  = a01 + 2u * 32768u;
            lds_fadd        (a01, __uint_as_float(u0 ^ flip));
            lds_fadd_off32k (a01, __uint_as_float(u1 ^ flip));
            lds_fadd        (a23, __uint_as_float(u2 ^ flip));
            lds_fadd_off32k (a23, __uint_as_float(u3 ^ flip));
        }
    }
    __syncthreads();
    for (int i = threadIdx.x; i < 4 * PROJ; i += 1024) {
        const int r  = i >> 13;
        const int pp = i & (PROJ - 1);
        unsafeAtomicAdd(&out[(size_t)(row0 + r) * PROJ + pp], acc[i] * 0.5f);
    }
}

// --------------------------------------------------------------- launch
extern "C" void kernel_launch(void* const* d_in, const int* in_sizes, int n_in,
                              void* d_out, int out_size, void* d_ws, size_t ws_size,
                              hipStream_t stream) {
    const float* x   = (const float*)d_in[0];
    const int4*  idx = (const int4*) d_in[1];
    const int4*  sgn = (const int4*) d_in[2];
    float*       out = (float*)d_out;

    // ws layout (bytes):
    //   xT bf16[D][64]            0          .. 67,108,864
    //   entries u16[256*SEG]      67,108,864 .. 71,663,616
    //   cnt u32[1024*256]         71,663,616 .. 72,712,192   (block-major)
    //   lofs u32[256*1024]        72,712,192 .. 73,760,768   (bucket-major)
    //   tot u32[256]              73,760,768 .. 73,761,792
    const size_t need = 73761792;
    if (ws_size >= need) {
        uint8_t*  ws      = (uint8_t*)d_ws;
        uint32_t* xT32    = (uint32_t*)ws;
        uint16_t* xT16    = (uint16_t*)ws;
        uint16_t* entries = (uint16_t*)(ws + 67108864);
        uint32_t* cnt     = (uint32_t*)(ws + 71663616);
        uint32_t* lofs    = (uint32_t*)(ws + 72712192);
        uint32_t* tot     = (uint32_t*)(ws + 73760768);

        k1_transpose_count<<<NBLK,  256, 0, stream>>>(x, idx, xT32, cnt);
        k2_scan           <<<NBUCK, 256, 0, stream>>>(cnt, lofs, tot);
        k3_scatter        <<<NBLK,  256, 0, stream>>>(idx, sgn, cnt, lofs, entries);
        k4_gather         <<<NBUCK, 512, 0, stream>>>(entries, lofs, tot, xT16, out);
    } else {
        // ws too small: R3 LDS-scatter path (passes at ~830 us)
        hipMemsetAsync(d_out, 0, (size_t)out_size * sizeof(float), stream);
        dim3 grid(16, 16);
        sjlt_scatter<<<grid, 1024, 0, stream>>>(x, idx, sgn, out);
    }
}

// Round 9
// 474.768 us; speedup vs baseline: 1.2310x; 1.0347x over previous
//
#include <hip/hip_runtime.h>

// SJLT projection: out[b, idx[d,j]] += x[b,d] * sign(d,j), * 1/sqrt(4)
// B=64, D=524288, P=8192, C=4.
//
// Measured walls (R1-R8):
//  - LDS atomics: ~3.16 cyc/lane, pipe-serialized regardless of conflicts.
//  - Global atomics: ~40ns each + 64B HBM write-through per line RMW.
//  - Random small global stores: 64B HBM write each.
//  - R8 K4: shfl(DS)+fat VALU addr math + 8 waves/CU -> latency-bound 237us.
// R9: block-major entries (no K2/K3), scalar-ized gather:
//  K1 transpose+count+local scan+stage+coalesced entry write (one pass)
//  K4 per-run vector load + readlane broadcast; entry fields in SGPRs;
//     xT load = SGPR base + precomputed lane offset; 2 blocks/bucket,
//     16 waves/CU; bf16 partials
//  K5 partial reduce -> out (full coverage, no memset)

constexpr int BATCH = 64;
constexpr int DIM   = 524288;
constexpr int PROJ  = 8192;
constexpr int NBLK  = 1024;         // d-chunks
constexpr int DPB   = DIM / NBLK;   // 512 d per chunk
constexpr int NBUCK = 256;          // buckets of 32 p's

__device__ __forceinline__ uint32_t f2bf(float f) {   // RNE f32 -> bf16 bits
    uint32_t u = __float_as_uint(f);
    return (u + 0x7fffu + ((u >> 16) & 1u)) >> 16;
}

// -------- K1: transpose x -> xT bf16 (*0.5) + per-block bucketed entries
// entries block-major: entries32[blk*1024 + w] packs 2 u16 entries
// entry = dloc<<6 | sign<<5 | ploc   (dloc 9b, sign 1b, ploc 5b)
// lbase_g[blk*257 + q] = exclusive start of bucket q's run; [256] = 2048.
__global__ __launch_bounds__(256) void k1_build(
    const float* __restrict__ x, const int4* __restrict__ idx4,
    const int4* __restrict__ sgn4, uint32_t* __restrict__ xT32,
    uint32_t* __restrict__ entries32, uint32_t* __restrict__ lbase_g)
{
    __shared__ float tile[64][65];
    __shared__ uint32_t lcnt[NBUCK];
    __shared__ uint32_t lb[NBUCK + 1];
    __shared__ uint32_t cur[NBUCK];
    __shared__ uint16_t staged[2048];

    const int t    = threadIdx.x;
    const int blk  = blockIdx.x;
    const int dblk = blk * DPB;

    lcnt[t] = 0;
    __syncthreads();

    const int4 ia = idx4[dblk + 2 * t];
    const int4 ib = idx4[dblk + 2 * t + 1];
    const int4 sa = sgn4[dblk + 2 * t];
    const int4 sb = sgn4[dblk + 2 * t + 1];

    atomicAdd(&lcnt[ia.x >> 5], 1u);
    atomicAdd(&lcnt[ia.y >> 5], 1u);
    atomicAdd(&lcnt[ia.z >> 5], 1u);
    atomicAdd(&lcnt[ia.w >> 5], 1u);
    atomicAdd(&lcnt[ib.x >> 5], 1u);
    atomicAdd(&lcnt[ib.y >> 5], 1u);
    atomicAdd(&lcnt[ib.z >> 5], 1u);
    atomicAdd(&lcnt[ib.w >> 5], 1u);

    for (int tt = 0; tt < 8; ++tt) {            // transpose 8 tiles of 64 d
        const int d0 = dblk + tt * 64;
        __syncthreads();
#pragma unroll
        for (int i = 0; i < 16; ++i) {
            const int fid = i * 256 + t;
            tile[fid >> 6][fid & 63] =
                x[(size_t)(fid >> 6) * DIM + d0 + (fid & 63)] * 0.5f;
        }
        __syncthreads();
#pragma unroll
        for (int i = 0; i < 8; ++i) {
            const int fid = i * 256 + t;
            const int dl = fid >> 5, k = fid & 31;
            xT32[(size_t)(d0 + dl) * 32 + k] =
                f2bf(tile[2 * k][dl]) | (f2bf(tile[2 * k + 1][dl]) << 16);
        }
    }
    __syncthreads();

    if (t < 64) {                               // wave-0 exclusive scan of lcnt
        uint32_t c4[4], s = 0;
#pragma unroll
        for (int i = 0; i < 4; ++i) { c4[i] = lcnt[t * 4 + i]; s += c4[i]; }
        uint32_t v = s;
#pragma unroll
        for (int off = 1; off < 64; off <<= 1) {
            uint32_t u = __shfl_up(v, off);
            if (t >= off) v += u;
        }
        uint32_t base = v - s;
#pragma unroll
        for (int i = 0; i < 4; ++i) { lb[t * 4 + i] = base; base += c4[i]; }
        if (t == 63) lb[256] = base;            // = 2048
    }
    __syncthreads();
    cur[t] = lb[t];
    __syncthreads();

    auto stage = [&](int p, int s, uint32_t dsh) {
        uint32_t pos = atomicAdd(&cur[(uint32_t)p >> 5], 1u);
        staged[pos] = (uint16_t)(dsh | ((uint32_t)(s & 1) << 5) | ((uint32_t)p & 31u));
    };
    const uint32_t dA = (uint32_t)(2 * t)     << 6;
    const uint32_t dB = (uint32_t)(2 * t + 1) << 6;
    stage(ia.x, sa.x, dA); stage(ia.y, sa.y, dA);
    stage(ia.z, sa.z, dA); stage(ia.w, sa.w, dA);
    stage(ib.x, sb.x, dB); stage(ib.y, sb.y, dB);
    stage(ib.z, sb.z, dB); stage(ib.w, sb.w, dB);
    __syncthreads();

    // coalesced write-out: 1024 u32 words + 257 lbase words
    const uint32_t* st32 = (const uint32_t*)staged;
    for (int i = t; i < 1024; i += 256)
        entries32[(size_t)blk * 1024 + i] = st32[i];
    lbase_g[(size_t)blk * 257 + t] = lb[t];
    if (t == 0) lbase_g[(size_t)blk * 257 + 256] = lb[256];
}

// -------- K4: gather. grid 512: bucket q = bid>>1, sub = bid&1.
// 8 waves; global wave g = sub*8+w walks blks g, g+16, ...
__global__ __launch_bounds__(512) void k4_gather(
    const uint32_t* __restrict__ entries32, const uint32_t* __restrict__ lbase_g,
    const uint16_t* __restrict__ xT16, uint16_t* __restrict__ part)
{
    __shared__ float acc[8][32 * 66];            // 67.6 KB -> 2 blocks/CU
    const int t    = threadIdx.x;
    const int w    = t >> 6;
    const int lane = t & 63;
    const int q    = blockIdx.x >> 1;
    const int sub  = blockIdx.x & 1;
    float* aw = acc[w];

    for (int i = t; i < 8 * 32 * 66; i += 512) ((float*)acc)[i] = 0.f;
    __syncthreads();

    const int g0 = sub * 8 + w;
    for (int blk = g0; blk < NBLK; blk += 16) {
        const uint32_t start = lbase_g[(size_t)blk * 257 + q];       // uniform
        const uint32_t end   = lbase_g[(size_t)blk * 257 + q + 1];
        if (start >= end) continue;
        const uint16_t* xTb = xT16 + ((size_t)blk << 15);            // blk*512*64
        const uint32_t* eb  = entries32 + (size_t)blk * 1024;
        const uint32_t i20 = start >> 1;
        const uint32_t i21 = (end + 1) >> 1;

        for (uint32_t c0 = i20; c0 < i21; c0 += 64) {    // runs ~4-5 words
            uint32_t nw = i21 - c0; if (nw > 64u) nw = 64u;
            uint32_t li = c0 + (uint32_t)lane;
            if (li > 1023u) li = 1023u;                  // stay in blk region
            const uint32_t ev = eb[li];                  // whole run, 1 load
            for (uint32_t j = 0; j < nw; ++j) {
                const uint32_t pr = __builtin_amdgcn_readlane(ev, (int)j); // SGPR
                const uint32_t gi = (c0 + j) << 1;       // entry idx of low half
                if (gi >= start) {                       // uniform branch
                    const uint32_t e  = pr & 0xffffu;
                    const uint32_t u  = (uint32_t)xTb[((e >> 6) << 6) + lane];
                    const uint32_t sm = ((e & 32u) ^ 32u) << 26;
                    aw[(e & 31u) * 66 + lane] += __uint_as_float((u << 16) ^ sm);
                }
                if (gi + 1 < end) {                      // uniform branch
                    const uint32_t e  = pr >> 16;
                    const uint32_t u  = (uint32_t)xTb[((e >> 6) << 6) + lane];
                    const uint32_t sm = ((e & 32u) ^ 32u) << 26;
                    aw[(e & 31u) * 66 + lane] += __uint_as_float((u << 16) ^ sm);
                }
            }
        }
    }
    __syncthreads();

    for (int i = t; i < 2048; i += 512) {        // reduce 8 wave-accs -> bf16
        const int pl = i >> 6, b = i & 63;
        float v = 0.f;
#pragma unroll
        for (int ww = 0; ww < 8; ++ww) v += acc[ww][pl * 66 + b];
        part[(size_t)blockIdx.x * 2048 + i] = (uint16_t)f2bf(v);
    }
}

// -------- K5: out[b][q*32+pl] = part[2q] + part[2q+1]
__global__ __launch_bounds__(256) void k5_reduce(
    const uint16_t* __restrict__ part, float* __restrict__ out)
{
    __shared__ float lds[32 * 65];
    const int q = blockIdx.x;
    const int t = threadIdx.x;
    for (int i = t; i < 2048; i += 256) {
        const uint32_t a = part[(size_t)(2 * q)     * 2048 + i];
        const uint32_t b = part[(size_t)(2 * q + 1) * 2048 + i];
        lds[(i >> 6) * 65 + (i & 63)] =
            __uint_as_float(a << 16) + __uint_as_float(b << 16);
    }
    __syncthreads();
#pragma unroll
    for (int pass = 0; pass < 8; ++pass) {
        const int idx = pass * 256 + t;
        const int b   = idx >> 5;
        const int pl  = idx & 31;
        out[(size_t)b * PROJ + q * 32 + pl] = lds[pl * 65 + b];
    }
}

// ------------------------------------------------- fallback (R3 scatter)
__device__ __forceinline__ void lds_fadd(uint32_t byte_addr, float v) {
    asm volatile("ds_add_f32 %0, %1" :: "v"(byte_addr), "v"(v) : "memory");
}
__device__ __forceinline__ void lds_fadd_off32k(uint32_t byte_addr, float v) {
    asm volatile("ds_add_f32 %0, %1 offset:32768" :: "v"(byte_addr), "v"(v) : "memory");
}

__global__ __launch_bounds__(1024) void sjlt_scatter(
    const float* __restrict__ x, const int4* __restrict__ idx4,
    const int4* __restrict__ sgn4, float* __restrict__ out)
{
    __shared__ float acc[4 * PROJ];
    for (int i = threadIdx.x; i < 4 * PROJ; i += 1024) acc[i] = 0.0f;
    __syncthreads();
    const int row0 = blockIdx.y * 4;
    const int dbeg = blockIdx.x * (DIM / 16);
    const uint32_t accBase = (uint32_t)(uintptr_t)(&acc[0]);
    const float* xr0 = x + (size_t)(row0 + 0) * DIM;
    const float* xr1 = x + (size_t)(row0 + 1) * DIM;
    const float* xr2 = x + (size_t)(row0 + 2) * DIM;
    const float* xr3 = x + (size_t)(row0 + 3) * DIM;
    for (int d = dbeg + (int)threadIdx.x; d < dbeg + DIM / 16; d += 1024) {
        const int4 iv = idx4[d];
        const int4 sv = sgn4[d];
        const uint32_t u0 = __float_as_uint(xr0[d]);
        const uint32_t u1 = __float_as_uint(xr1[d]);
        const uint32_t u2 = __float_as_uint(xr2[d]);
        const uint32_t u3 = __float_as_uint(xr3[d]);
        const int p[4] = {iv.x, iv.y, iv.z, iv.w};
        const int s[4] = {sv.x, sv.y, sv.z, sv.w};
#pragma unroll
        for (int j = 0; j < 4; ++j) {
            const uint32_t flip = (uint32_t)(s[j] ^ 1) << 31;
            const uint32_t a01  = accBase + ((uint32_t)p[j] << 2);
            const uint32_t a23  = a01 + 2u * 32768u;
            lds_fadd        (a01, __uint_as_float(u0 ^ flip));
            lds_fadd_off32k (a01, __uint_as_float(u1 ^ flip));
            lds_fadd        (a23, __uint_as_float(u2 ^ flip));
            lds_fadd_off32k (a23, __uint_as_float(u3 ^ flip));
        }
    }
    __syncthreads();
    for (int i = threadIdx.x; i < 4 * PROJ; i += 1024) {
        const int r  = i >> 13;
        const int pp = i & (PROJ - 1);
        unsafeAtomicAdd(&out[(size_t)(row0 + r) * PROJ + pp], acc[i] * 0.5f);
    }
}

// --------------------------------------------------------------- launch
extern "C" void kernel_launch(void* const* d_in, const int* in_sizes, int n_in,
                              void* d_out, int out_size, void* d_ws, size_t ws_size,
                              hipStream_t stream) {
    const float* x   = (const float*)d_in[0];
    const int4*  idx = (const int4*) d_in[1];
    const int4*  sgn = (const int4*) d_in[2];
    float*       out = (float*)d_out;

    // ws layout (bytes):
    //   xT bf16[D][64]         0          .. 67,108,864
    //   entries u32[1024*1024] 67,108,864 .. 71,303,168
    //   lbase u32[1024*257]    71,303,168 .. 72,355,840
    //   part bf16[512*2048]    72,355,840 .. 74,452,992
    const size_t need = 74452992;
    if (ws_size >= need) {
        uint8_t*  ws       = (uint8_t*)d_ws;
        uint32_t* xT32     = (uint32_t*)ws;
        uint16_t* xT16     = (uint16_t*)ws;
        uint32_t* entries  = (uint32_t*)(ws + 67108864);
        uint32_t* lbase    = (uint32_t*)(ws + 71303168);
        uint16_t* part     = (uint16_t*)(ws + 72355840);

        k1_build <<<NBLK,      256, 0, stream>>>(x, idx, sgn, xT32, entries, lbase);
        k4_gather<<<NBUCK * 2, 512, 0, stream>>>(entries, lbase, xT16, part);
        k5_reduce<<<NBUCK,     256, 0, stream>>>(part, out);
    } else {
        // ws too small: R3 LDS-scatter path (passes at ~830 us)
        hipMemsetAsync(d_out, 0, (size_t)out_size * sizeof(float), stream);
        dim3 grid(16, 16);
        sjlt_scatter<<<grid, 1024, 0, stream>>>(x, idx, sgn, out);
    }
}

// Round 10
// 443.591 us; speedup vs baseline: 1.3175x; 1.0703x over previous
//
#include <hip/hip_runtime.h>

// SJLT projection: out[b, idx[d,j]] += x[b,d] * sign(d,j), * 1/sqrt(4)
// B=64, D=524288, P=8192, C=4.
//
// Measured walls (R1-R9):
//  - LDS atomics ~3.16 cyc/lane (pipe-serialized); global atomics ~40ns +
//    64B HBM write-through; random small stores 64B each.
//  - R9 K4: per-entry load->wait->DS chain, ~1 load in flight -> 227us
//    invariant to occupancy. Fix: batch 12 loads before consuming.
//  - R9 K1 (fused transpose+stage) ~240us unexplained -> split to attribute.
// R10: k1a pure transpose | k1b entries build | k4 batched gather | k5 reduce.

constexpr int BATCH = 64;
constexpr int DIM   = 524288;
constexpr int PROJ  = 8192;
constexpr int NBLK  = 1024;         // d-chunks
constexpr int DPB   = DIM / NBLK;   // 512 d per chunk
constexpr int NBUCK = 256;          // buckets of 32 p's

__device__ __forceinline__ uint32_t f2bf(float f) {   // RNE f32 -> bf16 bits
    uint32_t u = __float_as_uint(f);
    return (u + 0x7fffu + ((u >> 16) & 1u)) >> 16;
}

// -------- k1a: pure transpose x -> xT bf16 (*0.5), packed 2 b / u32
__global__ __launch_bounds__(256) void k1a_transpose(
    const float* __restrict__ x, uint32_t* __restrict__ xT32)
{
    __shared__ float tile[64][65];
    const int d0 = blockIdx.x * 64;
    const int t  = threadIdx.x;
#pragma unroll
    for (int i = 0; i < 16; ++i) {
        const int fid = i * 256 + t;
        tile[fid >> 6][fid & 63] =
            x[(size_t)(fid >> 6) * DIM + d0 + (fid & 63)] * 0.5f;
    }
    __syncthreads();
#pragma unroll
    for (int i = 0; i < 8; ++i) {
        const int fid = i * 256 + t;          // linear u32 word id 0..2047
        const int dl = fid >> 5, k = fid & 31;
        xT32[(size_t)(d0 + dl) * 32 + k] =
            f2bf(tile[2 * k][dl]) | (f2bf(tile[2 * k + 1][dl]) << 16);
    }
}

// -------- k1b: per-block bucketed entries (block-major) + lbase
// entry u16 = dloc<<6 | sign<<5 | ploc  (dloc 9b, sign 1b, ploc 5b)
__global__ __launch_bounds__(256) void k1b_entries(
    const int4* __restrict__ idx4, const int4* __restrict__ sgn4,
    uint32_t* __restrict__ entries32, uint32_t* __restrict__ lbase_g)
{
    __shared__ uint32_t lcnt[NBUCK];
    __shared__ uint32_t lb[NBUCK + 1];
    __shared__ uint32_t cur[NBUCK];
    __shared__ uint16_t staged[2048];
    const int t    = threadIdx.x;
    const int blk  = blockIdx.x;
    const int dblk = blk * DPB;

    lcnt[t] = 0;
    __syncthreads();

    const int4 ia = idx4[dblk + 2 * t];
    const int4 ib = idx4[dblk + 2 * t + 1];
    const int4 sa = sgn4[dblk + 2 * t];
    const int4 sb = sgn4[dblk + 2 * t + 1];

    atomicAdd(&lcnt[ia.x >> 5], 1u);
    atomicAdd(&lcnt[ia.y >> 5], 1u);
    atomicAdd(&lcnt[ia.z >> 5], 1u);
    atomicAdd(&lcnt[ia.w >> 5], 1u);
    atomicAdd(&lcnt[ib.x >> 5], 1u);
    atomicAdd(&lcnt[ib.y >> 5], 1u);
    atomicAdd(&lcnt[ib.z >> 5], 1u);
    atomicAdd(&lcnt[ib.w >> 5], 1u);
    __syncthreads();

    if (t < 64) {                               // wave-0 exclusive scan
        uint32_t c4[4], s = 0;
#pragma unroll
        for (int i = 0; i < 4; ++i) { c4[i] = lcnt[t * 4 + i]; s += c4[i]; }
        uint32_t v = s;
#pragma unroll
        for (int off = 1; off < 64; off <<= 1) {
            uint32_t u = __shfl_up(v, off);
            if (t >= off) v += u;
        }
        uint32_t base = v - s;
#pragma unroll
        for (int i = 0; i < 4; ++i) { lb[t * 4 + i] = base; base += c4[i]; }
        if (t == 63) lb[256] = base;            // 2048
    }
    __syncthreads();
    cur[t] = lb[t];
    __syncthreads();

    auto stage = [&](int p, int s, uint32_t dsh) {
        uint32_t pos = atomicAdd(&cur[(uint32_t)p >> 5], 1u);
        staged[pos] = (uint16_t)(dsh | ((uint32_t)(s & 1) << 5) | ((uint32_t)p & 31u));
    };
    const uint32_t dA = (uint32_t)(2 * t)     << 6;
    const uint32_t dB = (uint32_t)(2 * t + 1) << 6;
    stage(ia.x, sa.x, dA); stage(ia.y, sa.y, dA);
    stage(ia.z, sa.z, dA); stage(ia.w, sa.w, dA);
    stage(ib.x, sb.x, dB); stage(ib.y, sb.y, dB);
    stage(ib.z, sb.z, dB); stage(ib.w, sb.w, dB);
    __syncthreads();

    const uint32_t* st32 = (const uint32_t*)staged;
    for (int i = t; i < 1024; i += 256)
        entries32[(size_t)blk * 1024 + i] = st32[i];
    lbase_g[(size_t)blk * 257 + t] = lb[t];
    if (t == 0) lbase_g[(size_t)blk * 257 + 256] = lb[256];
}

// -------- k4: gather. grid 512: bucket q = bid>>1, sub = bid&1.
// Batched inner: 12 xT loads issued before any consume (MLP fix).
__global__ __launch_bounds__(512) void k4_gather(
    const uint32_t* __restrict__ entries32, const uint32_t* __restrict__ lbase_g,
    const uint16_t* __restrict__ xT16, uint16_t* __restrict__ part)
{
    __shared__ float acc[8][32 * 66];            // 67.6 KB -> 2 blocks/CU
    const int t    = threadIdx.x;
    const int w    = t >> 6;
    const int lane = t & 63;
    const int q    = blockIdx.x >> 1;
    const int sub  = blockIdx.x & 1;
    float* aw = acc[w];

    for (int i = t; i < 8 * 32 * 66; i += 512) ((float*)acc)[i] = 0.f;
    __syncthreads();

    const int g0 = sub * 8 + w;
    for (int blk = g0; blk < NBLK; blk += 16) {
        const uint32_t start = lbase_g[(size_t)blk * 257 + q];       // uniform
        const uint32_t end   = lbase_g[(size_t)blk * 257 + q + 1];
        if (start >= end) continue;
        const uint16_t* xTb = xT16 + ((size_t)blk << 15);            // blk*512*64
        const uint32_t* eb  = entries32 + (size_t)blk * 1024;
        const uint32_t i20  = start >> 1;

        uint32_t li = i20 + (uint32_t)lane;
        if (li > 1023u) li = 1023u;
        const uint32_t ev = eb[li];      // run words live in low lanes

        uint32_t gi = start;
        while (gi < end) {                       // runs avg 8 -> 1 pass
            uint32_t cntE = end - gi; if (cntE > 12u) cntE = 12u;
            uint32_t us[12], es[12];
#pragma unroll
            for (int j = 0; j < 12; ++j) {       // phase A: issue all loads
                if ((uint32_t)j < cntE) {        // uniform branch
                    const uint32_t g  = gi + (uint32_t)j;
                    const uint32_t pr = __builtin_amdgcn_readlane(ev, (int)((g >> 1) - i20));
                    const uint32_t e  = (g & 1u) ? (pr >> 16) : (pr & 0xffffu);
                    es[j] = e;
                    us[j] = (uint32_t)xTb[((e >> 6) << 6) + lane];
                }
            }
#pragma unroll
            for (int j = 0; j < 12; ++j) {       // phase B: consume
                if ((uint32_t)j < cntE) {
                    const uint32_t e  = es[j];
                    const uint32_t sm = ((e & 32u) ^ 32u) << 26;
                    aw[(e & 31u) * 66 + lane] += __uint_as_float((us[j] << 16) ^ sm);
                }
            }
            gi += cntE;
        }
    }
    __syncthreads();

    for (int i = t; i < 2048; i += 512) {        // reduce 8 wave-accs -> bf16
        const int pl = i >> 6, b = i & 63;
        float v = 0.f;
#pragma unroll
        for (int ww = 0; ww < 8; ++ww) v += acc[ww][pl * 66 + b];
        part[(size_t)blockIdx.x * 2048 + i] = (uint16_t)f2bf(v);
    }
}

// -------- k5: out[b][q*32+pl] = part[2q] + part[2q+1]
__global__ __launch_bounds__(256) void k5_reduce(
    const uint16_t* __restrict__ part, float* __restrict__ out)
{
    __shared__ float lds[32 * 65];
    const int q = blockIdx.x;
    const int t = threadIdx.x;
    for (int i = t; i < 2048; i += 256) {
        const uint32_t a = part[(size_t)(2 * q)     * 2048 + i];
        const uint32_t b = part[(size_t)(2 * q + 1) * 2048 + i];
        lds[(i >> 6) * 65 + (i & 63)] =
            __uint_as_float(a << 16) + __uint_as_float(b << 16);
    }
    __syncthreads();
#pragma unroll
    for (int pass = 0; pass < 8; ++pass) {
        const int idx = pass * 256 + t;
        const int b   = idx >> 5;
        const int pl  = idx & 31;
        out[(size_t)b * PROJ + q * 32 + pl] = lds[pl * 65 + b];
    }
}

// ------------------------------------------------- fallback (R3 scatter)
__device__ __forceinline__ void lds_fadd(uint32_t byte_addr, float v) {
    asm volatile("ds_add_f32 %0, %1" :: "v"(byte_addr), "v"(v) : "memory");
}
__device__ __forceinline__ void lds_fadd_off32k(uint32_t byte_addr, float v) {
    asm volatile("ds_add_f32 %0, %1 offset:32768" :: "v"(byte_addr), "v"(v) : "memory");
}

__global__ __launch_bounds__(1024) void sjlt_scatter(
    const float* __restrict__ x, const int4* __restrict__ idx4,
    const int4* __restrict__ sgn4, float* __restrict__ out)
{
    __shared__ float acc[4 * PROJ];
    for (int i = threadIdx.x; i < 4 * PROJ; i += 1024) acc[i] = 0.0f;
    __syncthreads();
    const int row0 = blockIdx.y * 4;
    const int dbeg = blockIdx.x * (DIM / 16);
    const uint32_t accBase = (uint32_t)(uintptr_t)(&acc[0]);
    const float* xr0 = x + (size_t)(row0 + 0) * DIM;
    const float* xr1 = x + (size_t)(row0 + 1) * DIM;
    const float* xr2 = x + (size_t)(row0 + 2) * DIM;
    const float* xr3 = x + (size_t)(row0 + 3) * DIM;
    for (int d = dbeg + (int)threadIdx.x; d < dbeg + DIM / 16; d += 1024) {
        const int4 iv = idx4[d];
        const int4 sv = sgn4[d];
        const uint32_t u0 = __float_as_uint(xr0[d]);
        const uint32_t u1 = __float_as_uint(xr1[d]);
        const uint32_t u2 = __float_as_uint(xr2[d]);
        const uint32_t u3 = __float_as_uint(xr3[d]);
        const int p[4] = {iv.x, iv.y, iv.z, iv.w};
        const int s[4] = {sv.x, sv.y, sv.z, sv.w};
#pragma unroll
        for (int j = 0; j < 4; ++j) {
            const uint32_t flip = (uint32_t)(s[j] ^ 1) << 31;
            const uint32_t a01  = accBase + ((uint32_t)p[j] << 2);
            const uint32_t a23  = a01 + 2u * 32768u;
            lds_fadd        (a01, __uint_as_float(u0 ^ flip));
            lds_fadd_off32k (a01, __uint_as_float(u1 ^ flip));
            lds_fadd        (a23, __uint_as_float(u2 ^ flip));
            lds_fadd_off32k (a23, __uint_as_float(u3 ^ flip));
        }
    }
    __syncthreads();
    for (int i = threadIdx.x; i < 4 * PROJ; i += 1024) {
        const int r  = i >> 13;
        const int pp = i & (PROJ - 1);
        unsafeAtomicAdd(&out[(size_t)(row0 + r) * PROJ + pp], acc[i] * 0.5f);
    }
}

// --------------------------------------------------------------- launch
extern "C" void kernel_launch(void* const* d_in, const int* in_sizes, int n_in,
                              void* d_out, int out_size, void* d_ws, size_t ws_size,
                              hipStream_t stream) {
    const float* x   = (const float*)d_in[0];
    const int4*  idx = (const int4*) d_in[1];
    const int4*  sgn = (const int4*) d_in[2];
    float*       out = (float*)d_out;

    // ws layout (bytes):
    //   xT bf16[D][64]         0          .. 67,108,864
    //   entries u32[1024*1024] 67,108,864 .. 71,303,168
    //   lbase u32[1024*257]    71,303,168 .. 72,355,840
    //   part bf16[512*2048]    72,355,840 .. 74,452,992
    const size_t need = 74452992;
    if (ws_size >= need) {
        uint8_t*  ws       = (uint8_t*)d_ws;
        uint32_t* xT32     = (uint32_t*)ws;
        uint16_t* xT16     = (uint16_t*)ws;
        uint32_t* entries  = (uint32_t*)(ws + 67108864);
        uint32_t* lbase    = (uint32_t*)(ws + 71303168);
        uint16_t* part     = (uint16_t*)(ws + 72355840);

        k1a_transpose<<<DIM / 64,  256, 0, stream>>>(x, xT32);
        k1b_entries  <<<NBLK,      256, 0, stream>>>(idx, sgn, entries, lbase);
        k4_gather    <<<NBUCK * 2, 512, 0, stream>>>(entries, lbase, xT16, part);
        k5_reduce    <<<NBUCK,     256, 0, stream>>>(part, out);
    } else {
        // ws too small: R3 LDS-scatter path (passes at ~830 us)
        hipMemsetAsync(d_out, 0, (size_t)out_size * sizeof(float), stream);
        dim3 grid(16, 16);
        sjlt_scatter<<<grid, 1024, 0, stream>>>(x, idx, sgn, out);
    }
}